// Round 4
// baseline (501.139 us; speedup 1.0000x reference)
//
#include <hip/hip_runtime.h>
#include <hip/hip_bf16.h>

// CLIPAttention (B=16,T=1024,E=1024,H=16,DH=64) with 2D RoPE, bf16 MFMA path.
#define B_  16
#define T_  1024
#define E_  1024
#define H_  16
#define DH_ 64

typedef short s16x8 __attribute__((ext_vector_type(8)));   // 8 bf16 = 4 VGPRs (MFMA A/B frag)
typedef float f32x4 __attribute__((ext_vector_type(4)));   // MFMA C/D frag
typedef unsigned short u16x4 __attribute__((ext_vector_type(4)));  // 4 bf16 = 8B

__device__ __forceinline__ void async_cp16(const void* g, void* l) {
  __builtin_amdgcn_global_load_lds(
      (__attribute__((address_space(1))) unsigned int*)(g),
      (__attribute__((address_space(3))) unsigned int*)(l), 16, 0, 0);
}

__device__ __forceinline__ s16x8 frag8(const void* p) { return *(const s16x8*)p; }

__device__ __forceinline__ float fexp2(float x) {
#if __has_builtin(__builtin_amdgcn_exp2f)
  return __builtin_amdgcn_exp2f(x);
#else
  return exp2f(x);
#endif
}

// sin/cos of (2*pi*rev) via hw v_sin/v_cos; rev pre-fract'ed by caller
__device__ __forceinline__ float fsin2pi(float rev) {
#if __has_builtin(__builtin_amdgcn_sinf)
  return __builtin_amdgcn_sinf(rev);
#else
  return sinf(rev * 6.283185307179586f);
#endif
}
__device__ __forceinline__ float fcos2pi(float rev) {
#if __has_builtin(__builtin_amdgcn_cosf)
  return __builtin_amdgcn_cosf(rev);
#else
  return cosf(rev * 6.283185307179586f);
#endif
}

__device__ __forceinline__ unsigned short f2bu(float x) {
  __hip_bfloat16 h = __float2bfloat16(x);
  return *reinterpret_cast<unsigned short*>(&h);
}

// ---------------- cast fp32 -> bf16 (vectorized) ----------------
__global__ __launch_bounds__(256) void cast_f32_bf16(const float* __restrict__ in,
                                                     __hip_bfloat16* __restrict__ out,
                                                     int n4) {
  int i = blockIdx.x * 256 + threadIdx.x;
  if (i >= n4) return;
  float4 v = ((const float4*)in)[i];
  __hip_bfloat16* o = out + (size_t)i * 4;
  o[0] = __float2bfloat16(v.x);
  o[1] = __float2bfloat16(v.y);
  o[2] = __float2bfloat16(v.z);
  o[3] = __float2bfloat16(v.w);
}

// all 4 weight matrices in one launch (1024 blocks per 1Mx1 weight)
__global__ __launch_bounds__(256) void cast_w4(const float* __restrict__ w0, const float* __restrict__ w1,
                                               const float* __restrict__ w2, const float* __restrict__ w3,
                                               __hip_bfloat16* __restrict__ o0, __hip_bfloat16* __restrict__ o1,
                                               __hip_bfloat16* __restrict__ o2, __hip_bfloat16* __restrict__ o3) {
  int seg = blockIdx.x >> 10;
  const float* in = (seg == 0) ? w0 : (seg == 1) ? w1 : (seg == 2) ? w2 : w3;
  __hip_bfloat16* out = (seg == 0) ? o0 : (seg == 1) ? o1 : (seg == 2) ? o2 : o3;
  int i = (blockIdx.x & 1023) * 256 + threadIdx.x;
  float4 v = ((const float4*)in)[i];
  __hip_bfloat16* o = out + (size_t)i * 4;
  o[0] = __float2bfloat16(v.x);
  o[1] = __float2bfloat16(v.y);
  o[2] = __float2bfloat16(v.z);
  o[3] = __float2bfloat16(v.w);
}

// ======== shared GEMM core: 128x128 tile, BK=64, XOR-swizzled LDS ========
#define GEMM_CORE(A_, B_PTR_, K_)                                              \
  __shared__ __align__(16) __hip_bfloat16 As[128 * 64];                        \
  __shared__ __align__(16) __hip_bfloat16 Bs[128 * 64];                        \
  const int tid  = threadIdx.x;                                                \
  const int lane = tid & 63, wave = tid >> 6;                                  \
  const int col  = lane & 15, quad = lane >> 4;                                \
  const int wm = (wave >> 1) << 6, wn = (wave & 1) << 6;                       \
  const f32x4 fzero = {0.f, 0.f, 0.f, 0.f};                                    \
  f32x4 acc[4][4];                                                             \
  _Pragma("unroll") for (int i = 0; i < 4; i++)                                \
    _Pragma("unroll") for (int j = 0; j < 4; j++) acc[i][j] = fzero;           \
  const int r8 = lane >> 3;                                                    \
  const int kgs = (lane & 7) ^ (r8 & 7);                                       \
  const char* Asrc[4]; const char* Bsrc[4]; char* Adst[4]; char* Bdst[4];      \
  _Pragma("unroll") for (int u = 0; u < 4; u++) {                              \
    int ch = u * 4 + wave;                                                     \
    int row = ch * 8 + r8;                                                     \
    Asrc[u] = (const char*)(A_ + (size_t)(bm + row) * K_) + kgs * 16;          \
    Bsrc[u] = (const char*)(B_PTR_ + (size_t)(bn + row) * K_) + kgs * 16;      \
    Adst[u] = (char*)As + ch * 1024;                                           \
    Bdst[u] = (char*)Bs + ch * 1024;                                           \
  }                                                                            \
  const int sw0 = ((quad) ^ (col & 7)) * 16;                                   \
  const int sw1 = ((quad + 4) ^ (col & 7)) * 16;                               \
  for (int kt = 0; kt < (K_ >> 6); ++kt) {                                     \
    __syncthreads();                                                           \
    const int koff = kt * 128;                                                 \
    _Pragma("unroll") for (int u = 0; u < 4; u++) {                            \
      async_cp16(Asrc[u] + koff, Adst[u]);                                     \
      async_cp16(Bsrc[u] + koff, Bdst[u]);                                     \
    }                                                                          \
    __syncthreads();                                                           \
    s16x8 af[2][4], bf[2][4];                                                  \
    _Pragma("unroll") for (int i = 0; i < 4; i++) {                            \
      af[0][i] = frag8((const char*)As + (wm + i * 16 + col) * 128 + sw0);     \
      af[1][i] = frag8((const char*)As + (wm + i * 16 + col) * 128 + sw1);     \
    }                                                                          \
    _Pragma("unroll") for (int j = 0; j < 4; j++) {                            \
      bf[0][j] = frag8((const char*)Bs + (wn + j * 16 + col) * 128 + sw0);     \
      bf[1][j] = frag8((const char*)Bs + (wn + j * 16 + col) * 128 + sw1);     \
    }                                                                          \
    _Pragma("unroll") for (int i = 0; i < 4; i++)                              \
      _Pragma("unroll") for (int j = 0; j < 4; j++) {                          \
        acc[i][j] = __builtin_amdgcn_mfma_f32_16x16x32_bf16(af[0][i], bf[0][j], acc[i][j], 0, 0, 0); \
        acc[i][j] = __builtin_amdgcn_mfma_f32_16x16x32_bf16(af[1][i], bf[1][j], acc[i][j], 0, 0, 0); \
      }                                                                        \
  }

// ---------------- fused QKV GEMM + RoPE epilogue ----------------
// A: 16384x1024 bf16. Wqkv: 3072x1024 bf16 (Wq|Wk|Wv stacked).
// Q (pre-scaled by 0.125*log2e) and K rotated in-epilogue (2D RoPE, fp32 math);
// V written (b,h,d,t) transposed. Rotation partner d^1 lives in lane col^1 -> shfl_xor(1).
__global__ __launch_bounds__(256, 2) void gemm_qkv(const __hip_bfloat16* __restrict__ A,
                                                   const __hip_bfloat16* __restrict__ Wqkv,
                                                   const float* __restrict__ bq,
                                                   const float* __restrict__ bk,
                                                   const float* __restrict__ bv,
                                                   const int* __restrict__ pos,
                                                   __hip_bfloat16* __restrict__ Qb,
                                                   __hip_bfloat16* __restrict__ Kb,
                                                   __hip_bfloat16* __restrict__ Vt) {
  const int bm = (blockIdx.x & 127) << 7;
  const int bn = (blockIdx.x >> 7) << 7;
  GEMM_CORE(A, Wqkv, 1024)

  const int seg = bn >> 10;  // 0=Q 1=K 2=V (uniform per block)
  const float* bp = (seg == 0) ? bq : (seg == 1) ? bk : bv;
  float bcol[4];
#pragma unroll
  for (int j = 0; j < 4; j++) bcol[j] = bp[(bn & 1023) + wn + j * 16 + col];

  if (seg == 2) {
#pragma unroll
    for (int i = 0; i < 4; i++)
#pragma unroll
      for (int j = 0; j < 4; j++) {
        const int nc = (bn & 1023) + wn + j * 16 + col;
#pragma unroll
        for (int r = 0; r < 4; r++) {
          const int grow = bm + wm + i * 16 + quad * 4 + r;
          float v = acc[i][j][r] + bcol[j];
          int bb = grow >> 10, tt = grow & 1023;
          int hh = nc >> 6, dd = nc & 63;
          Vt[(((size_t)bb * H_ + hh) * DH_ + dd) * T_ + tt] = __float2bfloat16(v);
        }
      }
    return;
  }

  // RoPE: d = (j*16+col)&63 -> freq f = (j&1)*8 + (col>>1), half-select = j>>1.
  const float NL2T = -1.6609640474436811f;  // -log2(10000)/8
  const float inv0 = fexp2(NL2T * (float)(col >> 1));        // j even
  const float inv1 = fexp2(NL2T * (float)(8 + (col >> 1)));  // j odd
  const float sgn  = (col & 1) ? 1.f : -1.f;  // even d: v*c - p*s ; odd d: v*c + p*s
  const float R2PI = 0.15915494309189535f;
  const float QSC  = 0.18033688011112043f;    // 0.125 * log2(e) folded into Q
  const float osc  = (seg == 0) ? QSC : 1.f;
  __hip_bfloat16* Ob = (seg == 0) ? Qb : Kb;
  const int2* pos2 = (const int2*)pos;
#pragma unroll
  for (int i = 0; i < 4; i++) {
#pragma unroll
    for (int r = 0; r < 4; r++) {
      const int grow = bm + wm + i * 16 + quad * 4 + r;
      int2 pv = pos2[grow];
      float ph = (float)pv.x, pw = (float)pv.y;
      float cc[4], ss[4];
#pragma unroll
      for (int j = 0; j < 4; j++) {
        float p   = (j < 2) ? ph : pw;
        float inv = (j & 1) ? inv1 : inv0;
        float rev = p * inv * R2PI;
        rev -= floorf(rev);
        cc[j] = fcos2pi(rev);
        ss[j] = fsin2pi(rev);
      }
#pragma unroll
      for (int j = 0; j < 4; j++) {
        float v  = acc[i][j][r] + bcol[j];
        float vp = __shfl_xor(v, 1, 64);
        float rot = v * cc[j] + sgn * vp * ss[j];
        const int nc = (bn & 1023) + wn + j * 16 + col;
        Ob[(size_t)grow * 1024 + nc] = __float2bfloat16(rot * osc);
      }
    }
  }
}

// ---------------- output-proj GEMM: fp32 out ----------------
__global__ __launch_bounds__(256, 2) void gemm_out(const __hip_bfloat16* __restrict__ A,
                                                   const __hip_bfloat16* __restrict__ Bw,
                                                   const float* __restrict__ bias,
                                                   float* __restrict__ Cout) {
  const int bm = (blockIdx.x & 127) << 7;
  const int bn = (blockIdx.x >> 7) << 7;
  GEMM_CORE(A, Bw, 1024)

  float bcol[4];
#pragma unroll
  for (int j = 0; j < 4; j++) bcol[j] = bias[bn + wn + j * 16 + col];
#pragma unroll
  for (int i = 0; i < 4; i++)
#pragma unroll
    for (int j = 0; j < 4; j++) {
      const int gcol = bn + wn + j * 16 + col;
#pragma unroll
      for (int r = 0; r < 4; r++) {
        const int grow = bm + wm + i * 16 + quad * 4 + r;
        Cout[(size_t)grow * 1024 + gcol] = acc[i][j][r] + bcol[j];
      }
    }
}

// ---------------- flash attention, S^T formulation, fixed-max softmax ----------------
// S^T = K Q^T (A=K-frags, B=Q-frags): after exp each lane holds 4 CONSECUTIVE keys of
// one q-row -> P write = ds_write_b64, P read = ds_read_b128; l-sum = 2 scalars/lane
// + 2 shfls at the end; O store is packed 8B. Q pre-scaled by 0.125*log2e.
__global__ __launch_bounds__(256, 4) void attn_flash(const __hip_bfloat16* __restrict__ Q,
                                                     const __hip_bfloat16* __restrict__ Kt,
                                                     const __hip_bfloat16* __restrict__ Vt,
                                                     __hip_bfloat16* __restrict__ Oa) {
  __shared__ __align__(16) __hip_bfloat16 QP[128 * 72];  // 144B rows: Q tile, then P^T scratch
  __shared__ __align__(16) __hip_bfloat16 Ks[64 * 72];   // rows = key
  __shared__ __align__(16) __hip_bfloat16 Vs[64 * 72];   // rows = d, cols = key

  const int bid = blockIdx.x;          // 2048 = 256 (b,h) x 8 q-tiles
  const int bh = bid >> 3;
  const int b = bh >> 4, h = bh & 15;
  const int qt = bid & 7;
  const int tid = threadIdx.x;
  const int lane = tid & 63, wave = tid >> 6;
  const int col = lane & 15, quad = lane >> 4;

  const size_t qrow0 = (size_t)b * T_ + qt * 128;

#pragma unroll
  for (int cc = 0; cc < 4; ++cc) {
    int c = tid + cc * 256;
    int r = c >> 3, k8 = c & 7;
    const float4* src = (const float4*)((const char*)(Q + (qrow0 + r) * E_ + h * DH_)) + k8;
    *(float4*)((char*)QP + r * 144 + k8 * 16) = *src;
  }

  const f32x4 fzero = {0.f, 0.f, 0.f, 0.f};
  f32x4 o[2][4];           // o[g][jm][r] = O^T[d = jm*16+quad*4+r][q = col]
  float lr[2] = {0.f, 0.f};
#pragma unroll
  for (int g = 0; g < 2; g++)
#pragma unroll
    for (int j = 0; j < 4; j++) o[g][j] = fzero;
  s16x8 qf[2][2];
  char* Pw = (char*)QP + wave * 32 * 144;

  for (int kt2 = 0; kt2 < 16; ++kt2) {
    __syncthreads();
    const int kb = kt2 * 64;
#pragma unroll
    for (int cc = 0; cc < 4; ++cc) {
      int c = tid + cc * 256;
      if (c < 512) {
        int r = c >> 3, k8 = c & 7;
        const float4* src = (const float4*)((const char*)(Kt + ((size_t)b * T_ + kb + r) * E_ + h * DH_)) + k8;
        *(float4*)((char*)Ks + r * 144 + k8 * 16) = *src;
      } else {
        int c2 = c - 512;
        int d = c2 >> 3, k8 = c2 & 7;
        const float4* src = (const float4*)((const char*)(Vt + (((size_t)b * H_ + h) * DH_ + d) * T_ + kb)) + k8;
        *(float4*)((char*)Vs + d * 144 + k8 * 16) = *src;
      }
    }
    __syncthreads();
    if (kt2 == 0) {
#pragma unroll
      for (int g = 0; g < 2; g++) {
        qf[g][0] = frag8((const char*)QP + (g * 64 + wave * 16 + col) * 144 + quad * 16);
        qf[g][1] = frag8((const char*)QP + (g * 64 + wave * 16 + col) * 144 + 64 + quad * 16);
      }
      __syncthreads();  // all Q reads done before P writes clobber QP
    }
    s16x8 kf[4][2];
#pragma unroll
    for (int ktile = 0; ktile < 4; ktile++) {
      kf[ktile][0] = frag8((const char*)Ks + (ktile * 16 + col) * 144 + quad * 16);
      kf[ktile][1] = frag8((const char*)Ks + (ktile * 16 + col) * 144 + 64 + quad * 16);
    }
#pragma unroll
    for (int g = 0; g < 2; g++) {
#pragma unroll
      for (int ktile = 0; ktile < 4; ktile++) {
        f32x4 d = fzero;
        d = __builtin_amdgcn_mfma_f32_16x16x32_bf16(kf[ktile][0], qf[g][0], d, 0, 0, 0);
        d = __builtin_amdgcn_mfma_f32_16x16x32_bf16(kf[ktile][1], qf[g][1], d, 0, 0, 0);
        float p0 = fexp2(d[0]), p1 = fexp2(d[1]), p2 = fexp2(d[2]), p3 = fexp2(d[3]);
        lr[g] += (p0 + p1) + (p2 + p3);
        u16x4 pk = {f2bu(p0), f2bu(p1), f2bu(p2), f2bu(p3)};
        *(u16x4*)(Pw + (g * 16 + col) * 144 + ktile * 32 + quad * 8) = pk;
      }
    }
    s16x8 vf[4][2];
#pragma unroll
    for (int jm = 0; jm < 4; jm++) {
      vf[jm][0] = frag8((const char*)Vs + (jm * 16 + col) * 144 + quad * 16);
      vf[jm][1] = frag8((const char*)Vs + (jm * 16 + col) * 144 + 64 + quad * 16);
    }
#pragma unroll
    for (int g = 0; g < 2; g++) {
      s16x8 pf0 = frag8(Pw + (g * 16 + col) * 144 + quad * 16);
      s16x8 pf1 = frag8(Pw + (g * 16 + col) * 144 + 64 + quad * 16);
#pragma unroll
      for (int jm = 0; jm < 4; jm++) {
        o[g][jm] = __builtin_amdgcn_mfma_f32_16x16x32_bf16(vf[jm][0], pf0, o[g][jm], 0, 0, 0);
        o[g][jm] = __builtin_amdgcn_mfma_f32_16x16x32_bf16(vf[jm][1], pf1, o[g][jm], 0, 0, 0);
      }
    }
  }
#pragma unroll
  for (int g = 0; g < 2; g++) {
    lr[g] += __shfl_xor(lr[g], 16, 64);
    lr[g] += __shfl_xor(lr[g], 32, 64);
  }
#pragma unroll
  for (int g = 0; g < 2; g++) {
    float invl = 1.f / lr[g];
    size_t grow = qrow0 + g * 64 + wave * 16 + col;
    char* obase = (char*)(Oa + grow * E_ + h * DH_);
#pragma unroll
    for (int jm = 0; jm < 4; jm++) {
      u16x4 pk = {f2bu(o[g][jm][0] * invl), f2bu(o[g][jm][1] * invl),
                  f2bu(o[g][jm][2] * invl), f2bu(o[g][jm][3] * invl)};
      *(u16x4*)(obase + jm * 32 + quad * 8) = pk;
    }
  }
}

extern "C" void kernel_launch(void* const* d_in, const int* in_sizes, int n_in,
                              void* d_out, int out_size, void* d_ws, size_t ws_size,
                              hipStream_t stream) {
  const float* X   = (const float*)d_in[0];
  const int*   pos = (const int*)d_in[1];
  const float* Wq  = (const float*)d_in[2];
  const float* bq  = (const float*)d_in[3];
  const float* Wk  = (const float*)d_in[4];
  const float* bk  = (const float*)d_in[5];
  const float* Wv  = (const float*)d_in[6];
  const float* bv  = (const float*)d_in[7];
  const float* Wo  = (const float*)d_in[8];
  const float* bo  = (const float*)d_in[9];
  float* out = (float*)d_out;

  char* ws = (char*)d_ws;
  const size_t MB = 1024 * 1024;
  __hip_bfloat16* Xb    = (__hip_bfloat16*)(ws + 0 * MB);    // 32 MB
  __hip_bfloat16* Qb    = (__hip_bfloat16*)(ws + 32 * MB);   // 32 MB
  __hip_bfloat16* Kb    = (__hip_bfloat16*)(ws + 64 * MB);   // 32 MB
  __hip_bfloat16* Vtb   = (__hip_bfloat16*)(ws + 96 * MB);   // 32 MB (b,h,d,t)
  __hip_bfloat16* Wqkvb = (__hip_bfloat16*)(ws + 128 * MB);  // 6 MB (3072x1024)
  __hip_bfloat16* Wob   = (__hip_bfloat16*)(ws + 136 * MB);  // 2 MB
  __hip_bfloat16* Ab    = Xb;  // reuse: X dead after QKV projection

  cast_f32_bf16<<<16384, 256, 0, stream>>>(X, Xb, 4194304);
  cast_w4<<<4096, 256, 0, stream>>>(Wq, Wk, Wv, Wo,
                                    Wqkvb, Wqkvb + 1048576, Wqkvb + 2097152, Wob);

  gemm_qkv<<<3072, 256, 0, stream>>>(Xb, Wqkvb, bq, bk, bv, pos, Qb, Kb, Vtb);

  attn_flash<<<2048, 256, 0, stream>>>(Qb, Kb, Vtb, Ab);

  gemm_out<<<1024, 256, 0, stream>>>(Ab, Wob, bo, out);
}